// Round 4
// baseline (207.316 us; speedup 1.0000x reference)
//
#include <hip/hip_runtime.h>

#define D_FEAT 128
#define SCAN_BS 1024

// ================= CSR-bucketing path (no fp32 atomics) =================
//
// ws layout (4-byte words), N = nodes, E = edges, nb = ceil(N/1024):
//   cnt    [0,   N)       int    in-degree histogram (zeroed)
//   deg    [N,  2N)       float  out-degree (mode 0 only, zeroed)
//   off    [2N, 3N+1)     int    exclusive prefix of cnt (off[N] = E)
//   cursor [3N+1,4N+1)    int    bucket fill cursors (init = off)
//   norm   [4N+1,5N+1)    float  deg^-1/2 (mode 0)
//   bsum   [5N+1, +nb)    int    per-block sums
//   boff   [.., +nb)      int    exclusive scan of bsum
//   (pad to 8B)
//   epack  [.., +2E)      uint2  packed {src, scale_bits} bucketed by dst
//   hb     [.., +64N)     uint   bf16-packed h (2 feats/word)  [bf16 tier only]

__device__ __forceinline__ unsigned rne_bf16(float f) {
    unsigned u = __float_as_uint(f);
    return (u + 0x7FFFu + ((u >> 16) & 1u)) >> 16;   // round-to-nearest-even
}

__global__ void convert_kernel(const float* __restrict__ h, uint4* __restrict__ hb,
                               int nvec) {   // nvec = N*D/8
    int i = blockIdx.x * blockDim.x + threadIdx.x;
    if (i >= nvec) return;
    const float4* hp = (const float4*)h;
    float4 a = hp[2 * i], b = hp[2 * i + 1];
    uint4 r;
    r.x = (rne_bf16(a.y) << 16) | rne_bf16(a.x);
    r.y = (rne_bf16(a.w) << 16) | rne_bf16(a.z);
    r.z = (rne_bf16(b.y) << 16) | rne_bf16(b.x);
    r.w = (rne_bf16(b.w) << 16) | rne_bf16(b.z);
    hb[i] = r;
}

__global__ void hist_kernel(const int* __restrict__ src, const int* __restrict__ dst,
                            int* __restrict__ cnt, float* __restrict__ deg,
                            int E, const int* __restrict__ mode) {
    int e = blockIdx.x * blockDim.x + threadIdx.x;
    if (e >= E) return;
    atomicAdd(&cnt[dst[e]], 1);
    if (*mode != 1) atomicAdd(&deg[src[e]], 1.0f);
}

// Level 1: per-block exclusive scan of cnt -> off (block-local), block sums -> bsum
__global__ void block_scan_kernel(const int* __restrict__ cnt, int* __restrict__ off,
                                  int* __restrict__ bsum, int N) {
    __shared__ int sdata[SCAN_BS];
    int tid = threadIdx.x;
    int i = blockIdx.x * SCAN_BS + tid;
    int x = (i < N) ? cnt[i] : 0;
    sdata[tid] = x;
    __syncthreads();
    for (int ofs = 1; ofs < SCAN_BS; ofs <<= 1) {
        int v = (tid >= ofs) ? sdata[tid - ofs] : 0;
        __syncthreads();
        sdata[tid] += v;
        __syncthreads();
    }
    if (i < N) off[i] = sdata[tid] - x;          // block-local exclusive
    if (tid == SCAN_BS - 1) bsum[blockIdx.x] = sdata[tid];
}

// Level 2: scan the nb block sums
__global__ void scan_sums_kernel(const int* __restrict__ bsum, int* __restrict__ boff,
                                 int* __restrict__ offN, int nb) {
    if (nb <= 64) {
        int lane = threadIdx.x;                  // launched with 64 threads
        int x = (lane < nb) ? bsum[lane] : 0;
        int incl = x;
        #pragma unroll
        for (int ofs = 1; ofs < 64; ofs <<= 1) {
            int v = __shfl_up(incl, ofs, 64);
            if (lane >= ofs) incl += v;
        }
        if (lane < nb) boff[lane] = incl - x;
        if (lane == 63) *offN = incl;
    } else if (threadIdx.x == 0) {
        int acc = 0;
        for (int b = 0; b < nb; ++b) { boff[b] = acc; acc += bsum[b]; }
        *offN = acc;
    }
}

// Level 3: add block offsets, init cursors, compute norm (mode 0)
__global__ void finalize_kernel(int* __restrict__ off, int* __restrict__ cursor,
                                const int* __restrict__ boff, const float* __restrict__ deg,
                                float* __restrict__ norm, int N, const int* __restrict__ mode) {
    int i = blockIdx.x * blockDim.x + threadIdx.x;
    if (i >= N) return;
    int v = off[i] + boff[i / SCAN_BS];
    off[i] = v;
    cursor[i] = v;
    if (*mode != 1) norm[i] = rsqrtf(deg[i]);    // deg==0 -> inf, matches powf(0,-0.5)
}

// one 8B scattered store per edge instead of two 4B
__global__ void bucket_kernel(const int* __restrict__ src, const int* __restrict__ dst,
                              const float* __restrict__ w, const float* __restrict__ norm,
                              int* __restrict__ cursor, uint2* __restrict__ epack,
                              int E, const int* __restrict__ mode) {
    int e = blockIdx.x * blockDim.x + threadIdx.x;
    if (e >= E) return;
    int d = dst[e];
    int pos = atomicAdd(&cursor[d], 1);
    int s = src[e];
    float sc = (*mode == 1) ? w[e] : norm[s];
    epack[pos] = make_uint2((unsigned)s, __float_as_uint(sc));
}

// 32 lanes per dst node; lane owns 4 feats. bf16 h (8B/lane/edge).
__global__ void gather_bf16_kernel(const unsigned* __restrict__ hb, const int* __restrict__ off,
                                   const uint2* __restrict__ epack, const float* __restrict__ norm,
                                   float* __restrict__ out, int N, const int* __restrict__ mode) {
    long long gid = (long long)blockIdx.x * blockDim.x + threadIdx.x;
    int node = (int)(gid >> 5);
    int lane = (int)(gid & 31);
    if (node >= N) return;
    int beg = off[node], end = off[node + 1];
    float a0 = 0.f, a1 = 0.f, a2 = 0.f, a3 = 0.f;
    for (int j = beg; j < end; ++j) {
        uint2 m = epack[j];
        int s = (int)m.x;
        float sc = __uint_as_float(m.y);
        uint2 v = ((const uint2*)(hb + (long long)s * (D_FEAT / 2)))[lane];
        float f0 = __uint_as_float(v.x << 16);
        float f1 = __uint_as_float(v.x & 0xFFFF0000u);
        float f2 = __uint_as_float(v.y << 16);
        float f3 = __uint_as_float(v.y & 0xFFFF0000u);
        a0 += f0 * sc; a1 += f1 * sc; a2 += f2 * sc; a3 += f3 * sc;
    }
    float fin = (*mode == 1) ? 1.0f : norm[node];
    float4 r; r.x = a0 * fin; r.y = a1 * fin; r.z = a2 * fin; r.w = a3 * fin;
    ((float4*)(out + (long long)node * D_FEAT))[lane] = r;
}

// fp32 gather variant (tier 2, if ws too small for hb)
__global__ void gather_f32_kernel(const float* __restrict__ h, const int* __restrict__ off,
                                  const uint2* __restrict__ epack, const float* __restrict__ norm,
                                  float* __restrict__ out, int N, const int* __restrict__ mode) {
    long long gid = (long long)blockIdx.x * blockDim.x + threadIdx.x;
    int node = (int)(gid >> 5);
    int lane = (int)(gid & 31);
    if (node >= N) return;
    int beg = off[node], end = off[node + 1];
    float a0 = 0.f, a1 = 0.f, a2 = 0.f, a3 = 0.f;
    for (int j = beg; j < end; ++j) {
        uint2 m = epack[j];
        int s = (int)m.x;
        float sc = __uint_as_float(m.y);
        float4 v = ((const float4*)(h + (long long)s * D_FEAT))[lane];
        a0 += v.x * sc; a1 += v.y * sc; a2 += v.z * sc; a3 += v.w * sc;
    }
    float fin = (*mode == 1) ? 1.0f : norm[node];
    float4 r; r.x = a0 * fin; r.y = a1 * fin; r.z = a2 * fin; r.w = a3 * fin;
    ((float4*)(out + (long long)node * D_FEAT))[lane] = r;
}

// ================= fallback: atomic scatter =================

__global__ void fb_deg_kernel(const int* __restrict__ src, float* __restrict__ deg,
                              int E, const int* __restrict__ mode) {
    if (*mode == 1) return;
    int e = blockIdx.x * blockDim.x + threadIdx.x;
    if (e < E) atomicAdd(&deg[src[e]], 1.0f);
}
__global__ void fb_norm_kernel(const float* __restrict__ deg, float* __restrict__ norm,
                               int N, const int* __restrict__ mode) {
    if (*mode == 1) return;
    int i = blockIdx.x * blockDim.x + threadIdx.x;
    if (i < N) norm[i] = rsqrtf(deg[i]);
}
__global__ void fb_scatter_kernel(const float* __restrict__ h, const float* __restrict__ w,
                                  const int* __restrict__ src, const int* __restrict__ dst,
                                  const float* __restrict__ norm, float* __restrict__ out,
                                  int E, const int* __restrict__ mode) {
    long long gid = (long long)blockIdx.x * blockDim.x + threadIdx.x;
    int e = (int)(gid >> 5);
    int lane = (int)(gid & 31);
    if (e >= E) return;
    int s = src[e], d = dst[e];
    float scale = (*mode == 1) ? w[e] : norm[s];
    float4 v = ((const float4*)(h + (long long)s * D_FEAT))[lane];
    float* op = out + (long long)d * D_FEAT + lane * 4;
    atomicAdd(op + 0, v.x * scale);
    atomicAdd(op + 1, v.y * scale);
    atomicAdd(op + 2, v.z * scale);
    atomicAdd(op + 3, v.w * scale);
}
__global__ void fb_scale_kernel(float* __restrict__ out, const float* __restrict__ norm,
                                int N, const int* __restrict__ mode) {
    if (*mode == 1) return;
    int idx = blockIdx.x * blockDim.x + threadIdx.x;
    int total = N * (D_FEAT / 4);
    if (idx >= total) return;
    int node = idx / (D_FEAT / 4);
    float4* op = (float4*)out + idx;
    float4 v = *op;
    float nn = norm[node];
    v.x *= nn; v.y *= nn; v.z *= nn; v.w *= nn;
    *op = v;
}

extern "C" void kernel_launch(void* const* d_in, const int* in_sizes, int n_in,
                              void* d_out, int out_size, void* d_ws, size_t ws_size,
                              hipStream_t stream) {
    const float* h    = (const float*)d_in[0];
    const float* w    = (const float*)d_in[1];
    const int*   src  = (const int*)d_in[2];
    const int*   dst  = (const int*)d_in[3];
    const int*   mode = (const int*)d_in[4];

    int ND = in_sizes[0];
    int E  = in_sizes[1];
    int N  = ND / D_FEAT;
    int nb = (N + SCAN_BS - 1) / SCAN_BS;

    float* out = (float*)d_out;

    size_t epack_off = (size_t)5 * N + 1 + 2 * (size_t)nb;   // words
    epack_off = (epack_off + 1) & ~(size_t)1;                // 8B align
    size_t hb_off    = epack_off + 2 * (size_t)E;            // even
    size_t need_f32  = (epack_off + 2 * (size_t)E) * 4;
    size_t need_bf16 = (hb_off + (size_t)N * (D_FEAT / 2) / 1) * 4; // 64N words... (N*D/2 bf16 = N*64 words)
    // note: N*(D_FEAT/2) bf16 values = N*D_FEAT/4 words? careful: 2 bf16 per word ->
    // words = N*D_FEAT/2. Recompute:
    need_bf16 = (hb_off + (size_t)N * (D_FEAT / 2)) * 4;

    if (ws_size >= need_f32) {
        int*   cnt    = (int*)d_ws;
        float* deg    = (float*)(cnt + N);
        int*   off    = (int*)(deg + N);
        int*   cursor = off + N + 1;
        float* norm   = (float*)(cursor + N);
        int*   bsum   = (int*)(norm + N);
        // boff = bsum + nb
        int*   boff   = bsum + nb;
        uint2* epack  = (uint2*)((int*)d_ws + epack_off);
        unsigned* hb  = (unsigned*)((int*)d_ws + hb_off);

        bool use_bf16 = (ws_size >= need_bf16);

        // zero cnt + deg (adjacent, 2N words)
        hipMemsetAsync(d_ws, 0, (size_t)2 * N * sizeof(int), stream);

        if (use_bf16) {
            int nvec = N * D_FEAT / 8;
            convert_kernel<<<(nvec + 255) / 256, 256, 0, stream>>>(h, (uint4*)hb, nvec);
        }
        hist_kernel<<<(E + 255) / 256, 256, 0, stream>>>(src, dst, cnt, deg, E, mode);
        block_scan_kernel<<<nb, SCAN_BS, 0, stream>>>(cnt, off, bsum, N);
        scan_sums_kernel<<<1, 64, 0, stream>>>(bsum, boff, &off[N], nb);
        finalize_kernel<<<(N + 255) / 256, 256, 0, stream>>>(off, cursor, boff, deg,
                                                             norm, N, mode);
        bucket_kernel<<<(E + 255) / 256, 256, 0, stream>>>(src, dst, w, norm, cursor,
                                                           epack, E, mode);
        long long gt = (long long)N * 32;
        int gblocks = (int)((gt + 255) / 256);
        if (use_bf16) {
            gather_bf16_kernel<<<gblocks, 256, 0, stream>>>(hb, off, epack, norm,
                                                            out, N, mode);
        } else {
            gather_f32_kernel<<<gblocks, 256, 0, stream>>>(h, off, epack, norm,
                                                           out, N, mode);
        }
    } else {
        // fallback: atomic scatter
        float* deg  = (float*)d_ws;
        float* norm = deg + N;
        hipMemsetAsync(d_out, 0, (size_t)out_size * sizeof(float), stream);
        hipMemsetAsync(d_ws, 0, (size_t)N * sizeof(float), stream);
        fb_deg_kernel<<<(E + 255) / 256, 256, 0, stream>>>(src, deg, E, mode);
        fb_norm_kernel<<<(N + 255) / 256, 256, 0, stream>>>(deg, norm, N, mode);
        long long tt = (long long)E * 32;
        fb_scatter_kernel<<<(int)((tt + 255) / 256), 256, 0, stream>>>(h, w, src, dst,
                                                                       norm, out, E, mode);
        int st = N * (D_FEAT / 4);
        fb_scale_kernel<<<(st + 255) / 256, 256, 0, stream>>>(out, norm, N, mode);
    }
}